// Round 10
// baseline (464.048 us; speedup 1.0000x reference)
//
#include <hip/hip_runtime.h>
#include <hip/hip_bf16.h>

typedef __attribute__((ext_vector_type(8))) short short8v;
typedef __attribute__((ext_vector_type(8))) unsigned short ushort8v;
typedef __attribute__((ext_vector_type(4))) float f32x4;
typedef __attribute__((ext_vector_type(16))) float f32x16;

#define N_NBR 65536
#define INIT_DIM 512
#define HID 1024
#define BM 64
#define NBLK 3072   // 3 types x 1024 M-tiles; one type per block

static __device__ __forceinline__ unsigned short f2bf(float f) {
  unsigned int u = __float_as_uint(f);
  u += 0x7fff + ((u >> 16) & 1);   // round-to-nearest-even
  return (unsigned short)(u >> 16);
}

// Relayout W (3x [1024 n][512 k] f32) into 32x32x16-MFMA fragment order bf16:
// tile (t, nb 0..31, ks 0..31): the 1KB a wave reads is contiguous:
//   out[(((t*32+nb)*32)+ks)*512 + l*8 + j] = W_t[nb*32 + (l&31)][ks*16 + (l>>5)*8 + j]
__global__ __launch_bounds__(256) void k_convw(const float* __restrict__ wa,
                                               const float* __restrict__ wb,
                                               const float* __restrict__ wc,
                                               unsigned short* __restrict__ out) {
  int g = blockIdx.x * 256 + threadIdx.x;   // 0..196607
  int l = g & 63;
  int blk = g >> 6;            // t*1024 + nb*32 + ks
  int ks = blk & 31;
  int nb = (blk >> 5) & 31;
  int t = blk >> 10;
  const float* src = (t == 0) ? wa : (t == 1) ? wb : wc;
  int n = nb * 32 + (l & 31);
  int k0 = ks * 16 + (l >> 5) * 8;
  const f32x4* p = (const f32x4*)(src + (size_t)n * INIT_DIM + k0);
  f32x4 a = p[0], b = p[1];
  ushort8v v;
  v[0]=f2bf(a.x); v[1]=f2bf(a.y); v[2]=f2bf(a.z); v[3]=f2bf(a.w);
  v[4]=f2bf(b.x); v[5]=f2bf(b.y); v[6]=f2bf(b.z); v[7]=f2bf(b.w);
  *(ushort8v*)(out + (size_t)g * 8) = v;
}

// Main: 32x32x16 MFMA, mf=2 x nf=2, 4 N-passes. R9 + explicit software
// pipeline: B-prefetch ring depth 4 (covers ~200-300cyc L2 latency with
// ~516cyc of MFMA), A-ring depth 2 (ds_read ~120cyc). Ring slots are
// compile-time indexed (full unroll) so they stay in registers; slot reuse
// (WAR dep) caps compiler hoisting => no spill. Budget: ~150 VGPR + 64
// AGPR <= 256 keeps 2 waves/SIMD (R9: 88+64, occupancy 21.8%).
__global__ __launch_bounds__(256) void k_main(
    const float* __restrict__ fa, const float* __restrict__ fb, const float* __restrict__ fc,
    const int* __restrict__ na, const int* __restrict__ nb_, const int* __restrict__ nc__,
    const float* __restrict__ b1a, const float* __restrict__ b1b, const float* __restrict__ b1c,
    const unsigned short* __restrict__ wbf,   // [3][32 nb][32 ks][512] fragment-ordered bf16
    float* __restrict__ partials) {           // [NBLK][HID]
  __shared__ __align__(16) unsigned short Asm[BM * INIT_DIM];  // 64 KB
  __shared__ int idxs[BM];

  int bx = blockIdx.x;
  int t = bx >> 10;
  int mtile = bx & 1023;
  const float* feat = (t == 0) ? fa : (t == 1) ? fb : fc;
  const int*   nbr  = (t == 0) ? na : (t == 1) ? nb_ : nc__;
  const float* bias = (t == 0) ? b1a : (t == 1) ? b1b : b1c;
  const unsigned short* Wf = wbf + (size_t)t * (HID * INIT_DIM);

  int tid = threadIdx.x;
  if (tid < BM) idxs[tid] = nbr[mtile * BM + tid];
  __syncthreads();

  // Stage A: 64 rows x 512 f32 -> bf16 into LDS, 5-bit XOR swizzle (nt loads).
  #pragma unroll 4
  for (int it = 0; it < 16; ++it) {
    int i = it * 256 + tid;     // chunk of 8 floats
    int r = i >> 6;
    int ck = i & 63;
    const float* rowp = feat + (size_t)idxs[r] * INIT_DIM + ck * 8;
    f32x4 a = __builtin_nontemporal_load((const f32x4*)rowp);
    f32x4 b = __builtin_nontemporal_load(((const f32x4*)rowp) + 1);
    ushort8v v;
    v[0]=f2bf(a.x); v[1]=f2bf(a.y); v[2]=f2bf(a.z); v[3]=f2bf(a.w);
    v[4]=f2bf(b.x); v[5]=f2bf(b.y); v[6]=f2bf(b.z); v[7]=f2bf(b.w);
    int byte = r * 1024 + ((ck * 16) ^ ((r & 31) << 4));
    *(ushort8v*)((char*)Asm + byte) = v;
  }
  __syncthreads();

  int wave = tid >> 6;
  int lane = tid & 63;
  int l31 = lane & 31, hi = lane >> 5;

  // A read: lane reads A[row = i*32 + l31][k = ks*16 + hi*8 ..+8].
  // byte = row*1024 + ((ks*32 + hi*16) ^ (l31<<4)). Bit-split (disjoint):
  //   bit4:  (hi<<4) ^ (swz&16)      [precomputed into abase]
  //   bits>=5: (ks<<5) ^ (swz&0x1E0) [kcol per ks]
  unsigned int swz = (unsigned)l31 << 4;
  unsigned int abase = (unsigned)l31 * 1024u + (((unsigned)hi << 4) ^ (swz & 16u));
  unsigned int swzhi = swz & 0x1E0u;

  #pragma unroll
  for (int p = 0; p < 4; ++p) {
    // B base: nb index = wave*8 + p*2 + j ; offset (nb*32 + ks)*512 + lane*8
    const unsigned short* pB0 =
        Wf + (((size_t)(wave * 8 + p * 2)) << 14) + lane * 8;

    f32x16 acc[2][2] = {};     // 64 AGPR

    // Prologue: fill B ring (depth 4) and A ring (depth 2).
    short8v Bring[4][2];
    #pragma unroll
    for (int d = 0; d < 4; ++d) {
      Bring[d][0] = *(const short8v*)(pB0 + (d << 9));
      Bring[d][1] = *(const short8v*)(pB0 + (1 << 14) + (d << 9));
    }
    short8v Aring[2][2];
    #pragma unroll
    for (int d = 0; d < 2; ++d) {
      unsigned int kcol = (((unsigned)d) << 5) ^ swzhi;
      Aring[d][0] = *(const short8v*)((const char*)Asm + (abase + kcol));
      Aring[d][1] = *(const short8v*)((const char*)Asm + (abase + 32768u + kcol));
    }

    #pragma unroll
    for (int ks = 0; ks < 32; ++ks) {     // FULL unroll: ring idx compile-time
      short8v b0 = Bring[ks & 3][0], b1 = Bring[ks & 3][1];
      if (ks + 4 < 32) {
        Bring[ks & 3][0] = *(const short8v*)(pB0 + ((ks + 4) << 9));
        Bring[ks & 3][1] = *(const short8v*)(pB0 + (1 << 14) + ((ks + 4) << 9));
      }
      short8v a0 = Aring[ks & 1][0], a1 = Aring[ks & 1][1];
      if (ks + 2 < 32) {
        unsigned int kcol = (((unsigned)(ks + 2)) << 5) ^ swzhi;
        Aring[ks & 1][0] = *(const short8v*)((const char*)Asm + (abase + kcol));
        Aring[ks & 1][1] = *(const short8v*)((const char*)Asm + (abase + 32768u + kcol));
      }
      acc[0][0] = __builtin_amdgcn_mfma_f32_32x32x16_bf16(a0, b0, acc[0][0], 0, 0, 0);
      acc[0][1] = __builtin_amdgcn_mfma_f32_32x32x16_bf16(a0, b1, acc[0][1], 0, 0, 0);
      acc[1][0] = __builtin_amdgcn_mfma_f32_32x32x16_bf16(a1, b0, acc[1][0], 0, 0, 0);
      acc[1][1] = __builtin_amdgcn_mfma_f32_32x32x16_bf16(a1, b1, acc[1][1], 0, 0, 0);
    }

    // Epilogue: bias + relu + column-sum over 64 rows, store partial.
    // C layout (32x32): col = l31, row = (reg&3) + 8*(reg>>2) + 4*hi (+ 32*i).
    #pragma unroll
    for (int j = 0; j < 2; ++j) {
      int n = wave * 256 + p * 64 + j * 32 + l31;
      float b = bias[n];
      float s = 0.f;
      #pragma unroll
      for (int i = 0; i < 2; ++i)
        #pragma unroll
        for (int r = 0; r < 16; ++r) {
          float v = acc[i][j][r] + b;
          s += (v > 0.f) ? v : 0.f;
        }
      s += __shfl_xor(s, 32);
      if (hi == 0) partials[(size_t)bx * HID + n] = s;
    }
  }
}

// Column-sum of partials [NBLK][HID] -> acc[HID]. 16 blocks x 64 cols.
__global__ __launch_bounds__(256) void k_reduce(const float* __restrict__ partials,
                                                float* __restrict__ acc) {
  __shared__ float red[4][64];
  int tid = threadIdx.x;
  int c = tid & 63, rg = tid >> 6;
  int col = blockIdx.x * 64 + c;
  float s = 0.f;
  #pragma unroll 4
  for (int r = rg; r < NBLK; r += 4)
    s += partials[(size_t)r * HID + col];
  red[rg][c] = s;
  __syncthreads();
  if (rg == 0) acc[col] = red[0][c] + red[1][c] + red[2][c] + red[3][c];
}

// pooled = acc/196608 ; feat_all = relu ; logits = feat_all @ Wc.T + bc
__global__ __launch_bounds__(256) void k_final(const float* __restrict__ acc,
                                               const float* __restrict__ Wc,
                                               const float* __restrict__ bc,
                                               float* __restrict__ out) {
  __shared__ float fall[HID];
  int tid = threadIdx.x;
  const float inv = 1.f / (3.f * (float)N_NBR);
  for (int i = tid; i < HID; i += 256) {
    float p = acc[i] * inv;
    fall[i] = (p > 0.f) ? p : 0.f;
  }
  __syncthreads();
  int o = tid >> 2, q = tid & 3;
  const f32x4* w = (const f32x4*)(Wc + (size_t)o * HID + q * 256);
  const f32x4* f = (const f32x4*)(fall + q * 256);
  float s = 0.f;
  #pragma unroll 4
  for (int k = 0; k < 64; ++k) {
    f32x4 wv = w[k], fv = f[k];
    s += wv.x * fv.x + wv.y * fv.y + wv.z * fv.z + wv.w * fv.w;
  }
  s += __shfl_xor(s, 1);
  s += __shfl_xor(s, 2);
  if (q == 0) out[o] = s + bc[o];
}

extern "C" void kernel_launch(void* const* d_in, const int* in_sizes, int n_in,
                              void* d_out, int out_size, void* d_ws, size_t ws_size,
                              hipStream_t stream) {
  // inputs: 0 feat(unused), 1 fa, 2 na, 3 W1a, 4 b1a, 5 fb, 6 nb, 7 W1b, 8 b1b,
  //         9 fc, 10 nc, 11 W1c, 12 b1c, 13 Wc, 14 bc
  const float* fa  = (const float*)d_in[1];
  const int*   na  = (const int*)d_in[2];
  const float* W1a = (const float*)d_in[3];
  const float* b1a = (const float*)d_in[4];
  const float* fb  = (const float*)d_in[5];
  const int*   nb  = (const int*)d_in[6];
  const float* W1b = (const float*)d_in[7];
  const float* b1b = (const float*)d_in[8];
  const float* fc  = (const float*)d_in[9];
  const int*   nc  = (const int*)d_in[10];
  const float* W1c = (const float*)d_in[11];
  const float* b1c = (const float*)d_in[12];
  const float* Wc  = (const float*)d_in[13];
  const float* bc  = (const float*)d_in[14];
  float* out = (float*)d_out;

  float* acc = (float*)d_ws;                                          // 1024 f32
  unsigned short* wbf = (unsigned short*)((char*)d_ws + 4096);        // 3 MB bf16 fragment-ordered
  float* partials = (float*)((char*)d_ws + 4096 + 3 * HID * INIT_DIM * sizeof(unsigned short)); // 12.6 MB

  k_convw<<<768, 256, 0, stream>>>(W1a, W1b, W1c, wbf);
  k_main<<<NBLK, 256, 0, stream>>>(fa, fb, fc, na, nb, nc, b1a, b1b, b1c, wbf, partials);
  k_reduce<<<16, 256, 0, stream>>>(partials, acc);
  k_final<<<1, 256, 0, stream>>>(acc, Wc, bc, out);
}

// Round 11
// 315.584 us; speedup vs baseline: 1.4704x; 1.4704x over previous
//
#include <hip/hip_runtime.h>
#include <hip/hip_bf16.h>

typedef __attribute__((ext_vector_type(8))) short short8v;
typedef __attribute__((ext_vector_type(8))) unsigned short ushort8v;
typedef __attribute__((ext_vector_type(4))) float f32x4;
typedef __attribute__((ext_vector_type(16))) float f32x16;

#define N_NBR 65536
#define INIT_DIM 512
#define HID 1024
#define BM 64
#define NTILE 3072    // 3 types x 1024 M-tiles
#define NBLOCK 256    // persistent-ish: one block per CU
#define TPB 12        // tiles per block (3072/256)

static __device__ __forceinline__ unsigned short f2bf(float f) {
  unsigned int u = __float_as_uint(f);
  u += 0x7fff + ((u >> 16) & 1);   // round-to-nearest-even
  return (unsigned short)(u >> 16);
}

// Relayout W (3x [1024 n][512 k] f32) into 32x32x16-MFMA fragment order bf16:
// tile (t, nb 0..31, ks 0..31): the 1KB a wave reads is contiguous:
//   out[(((t*32+nb)*32)+ks)*512 + l*8 + j] = W_t[nb*32 + (l&31)][ks*16 + (l>>5)*8 + j]
__global__ __launch_bounds__(256) void k_convw(const float* __restrict__ wa,
                                               const float* __restrict__ wb,
                                               const float* __restrict__ wc,
                                               unsigned short* __restrict__ out) {
  int g = blockIdx.x * 256 + threadIdx.x;   // 0..196607
  int l = g & 63;
  int blk = g >> 6;            // t*1024 + nb*32 + ks
  int ks = blk & 31;
  int nb = (blk >> 5) & 31;
  int t = blk >> 10;
  const float* src = (t == 0) ? wa : (t == 1) ? wb : wc;
  int n = nb * 32 + (l & 31);
  int k0 = ks * 16 + (l >> 5) * 8;
  const f32x4* p = (const f32x4*)(src + (size_t)n * INIT_DIM + k0);
  f32x4 a = p[0], b = p[1];
  ushort8v v;
  v[0]=f2bf(a.x); v[1]=f2bf(a.y); v[2]=f2bf(a.z); v[3]=f2bf(a.w);
  v[4]=f2bf(b.x); v[5]=f2bf(b.y); v[6]=f2bf(b.z); v[7]=f2bf(b.w);
  *(ushort8v*)(out + (size_t)g * 8) = v;
}

// Main: 256 blocks x 512 threads (8 waves = 2/SIMD), 12 tiles each, LDS
// double-buffer (2 x 64KB). Per tile: issue next-tile gather A -> PASS0
// (covers A latency) -> write A, issue B -> PASS1 (covers B) -> write B,
// preload next idx -> ONE barrier. R9's K-loop kept verbatim (compiler-
// scheduled; explicit rings regressed 3x). __launch_bounds__(512,2) caps
// total regs at 256 (2 waves/SIMD floor) without R4's 128-cap spill trap.
__global__ __launch_bounds__(512, 2) void k_main(
    const float* __restrict__ fa, const float* __restrict__ fb, const float* __restrict__ fc,
    const int* __restrict__ na, const int* __restrict__ nb_, const int* __restrict__ nc__,
    const float* __restrict__ b1a, const float* __restrict__ b1b, const float* __restrict__ b1c,
    const unsigned short* __restrict__ wbf,   // [3][32 nb][32 ks][512] fragment-ordered bf16
    float* __restrict__ partials) {           // [NTILE][HID]
  __shared__ __align__(16) unsigned short Asm[2][BM * INIT_DIM];  // 2 x 64 KB

  int bx = blockIdx.x;
  int tid = threadIdx.x;
  int wave = tid >> 6;          // 0..7
  int lane = tid & 63;
  int l31 = lane & 31, hi = lane >> 5;
  int rowbase = wave;           // staging row group
  int ck = lane;                // staging column chunk (8 floats each)

  auto featsel = [&](int t) { return (t == 0) ? fa : (t == 1) ? fb : fc; };
  auto nbrsel  = [&](int t) { return (t == 0) ? na : (t == 1) ? nb_ : nc__; };
  auto biassel = [&](int t) { return (t == 0) ? b1a : (t == 1) ? b1b : b1c; };

  // A-read swizzle algebra (R9): byte = row*1024 + ((ks*32+hi*16) ^ (l31<<4))
  unsigned int swz = (unsigned)l31 << 4;
  unsigned int abase = (unsigned)l31 * 1024u + (((unsigned)hi << 4) ^ (swz & 16u));
  unsigned int swzhi = swz & 0x1E0u;

  int tile0 = bx * TPB;
  int idxr[8];       // next tile's row indices (chunk c -> row c*8+rowbase)
  f32x4 hold[8];     // in-flight gather regs (4 chunks x 2 f32x4)

  // ---- prologue: stage tile0 into Asm[0]; preload idxr for tile1.
  {
    int t0 = tile0 >> 10, mt0 = tile0 & 1023;
    const int* nbr0 = nbrsel(t0);
    const float* feat0 = featsel(t0);
    #pragma unroll
    for (int c = 0; c < 8; ++c) idxr[c] = nbr0[mt0 * 64 + c * 8 + rowbase];
    #pragma unroll
    for (int g = 0; g < 2; ++g) {
      #pragma unroll
      for (int c = 0; c < 4; ++c) {
        const float* rp = feat0 + (size_t)idxr[g * 4 + c] * INIT_DIM + ck * 8;
        hold[c * 2]     = __builtin_nontemporal_load((const f32x4*)rp);
        hold[c * 2 + 1] = __builtin_nontemporal_load((const f32x4*)rp + 1);
      }
      #pragma unroll
      for (int c = 0; c < 4; ++c) {
        int r = (g * 4 + c) * 8 + rowbase;
        f32x4 a = hold[c * 2], b2 = hold[c * 2 + 1];
        ushort8v v;
        v[0]=f2bf(a.x); v[1]=f2bf(a.y); v[2]=f2bf(a.z); v[3]=f2bf(a.w);
        v[4]=f2bf(b2.x); v[5]=f2bf(b2.y); v[6]=f2bf(b2.z); v[7]=f2bf(b2.w);
        unsigned byte = (unsigned)r * 1024u + (((unsigned)ck * 16u) ^ ((unsigned)(r & 31) << 4));
        *(ushort8v*)((char*)&Asm[0][0] + byte) = v;
      }
    }
    int t1 = (tile0 + 1) >> 10, mt1 = (tile0 + 1) & 1023;
    const int* nbr1 = nbrsel(t1);
    #pragma unroll
    for (int c = 0; c < 8; ++c) idxr[c] = nbr1[mt1 * 64 + c * 8 + rowbase];
  }
  __syncthreads();

  for (int q = 0; q < TPB; ++q) {
    int tile_id = tile0 + q;
    int t = tile_id >> 10;
    const unsigned short* Wf = wbf + (size_t)t * (HID * INIT_DIM);
    const float* bias = biassel(t);
    unsigned rdoff = (unsigned)(q & 1) * 65536u;
    char* wrbase = (char*)&Asm[0][0] + (unsigned)((q & 1) ^ 1) * 65536u;
    bool pf = (q + 1 < TPB);
    const float* featn = pf ? featsel((tile_id + 1) >> 10) : fa;

    // One K-pass over 64 cols-pair (nf=2) at pass p; R9's inner loop verbatim.
    auto do_pass = [&](int p) {
      const unsigned short* pB0 = Wf + (((size_t)(wave * 4 + p * 2)) << 14) + lane * 8;
      f32x16 acc[2][2] = {};
      #pragma unroll 4
      for (int ks = 0; ks < 32; ++ks) {
        short8v Bf[2];
        #pragma unroll
        for (int j = 0; j < 2; ++j)
          Bf[j] = *(const short8v*)(pB0 + (j << 14) + (ks << 9));
        unsigned kcol = (((unsigned)ks << 5) ^ swzhi);
        short8v Af[2];
        #pragma unroll
        for (int i = 0; i < 2; ++i)
          Af[i] = *(const short8v*)((const char*)&Asm[0][0] + rdoff + abase + (unsigned)(i * 32768) + kcol);
        #pragma unroll
        for (int i = 0; i < 2; ++i)
          #pragma unroll
          for (int j = 0; j < 2; ++j)
            acc[i][j] = __builtin_amdgcn_mfma_f32_32x32x16_bf16(Af[i], Bf[j], acc[i][j], 0, 0, 0);
      }
      // Epilogue: bias + relu + col-sum over 64 rows -> partial store.
      #pragma unroll
      for (int j = 0; j < 2; ++j) {
        int n = wave * 128 + p * 64 + j * 32 + l31;
        float b = bias[n];
        float s = 0.f;
        #pragma unroll
        for (int i = 0; i < 2; ++i)
          #pragma unroll
          for (int r = 0; r < 16; ++r) {
            float v = acc[i][j][r] + b;
            s += (v > 0.f) ? v : 0.f;
          }
        s += __shfl_xor(s, 32);
        if (hi == 0) partials[(size_t)tile_id * HID + n] = s;
      }
    };

    auto issue_group = [&](int g) {
      #pragma unroll
      for (int c = 0; c < 4; ++c) {
        const float* rp = featn + (size_t)idxr[g * 4 + c] * INIT_DIM + ck * 8;
        hold[c * 2]     = __builtin_nontemporal_load((const f32x4*)rp);
        hold[c * 2 + 1] = __builtin_nontemporal_load((const f32x4*)rp + 1);
      }
    };
    auto write_group = [&](int g) {
      #pragma unroll
      for (int c = 0; c < 4; ++c) {
        int r = (g * 4 + c) * 8 + rowbase;
        f32x4 a = hold[c * 2], b2 = hold[c * 2 + 1];
        ushort8v v;
        v[0]=f2bf(a.x); v[1]=f2bf(a.y); v[2]=f2bf(a.z); v[3]=f2bf(a.w);
        v[4]=f2bf(b2.x); v[5]=f2bf(b2.y); v[6]=f2bf(b2.z); v[7]=f2bf(b2.w);
        unsigned byte = (unsigned)r * 1024u + (((unsigned)ck * 16u) ^ ((unsigned)(r & 31) << 4));
        *(ushort8v*)(wrbase + byte) = v;
      }
    };

    if (pf) issue_group(0);          // gather A in flight under PASS0
    do_pass(0);
    if (pf) { write_group(0); issue_group(1); }   // B in flight under PASS1
    do_pass(1);
    if (pf) {
      write_group(1);
      if (q + 2 < TPB) {             // idx for tile q+2, covered by barrier+next PASS0
        int tn2 = tile_id + 2;
        const int* nbrn = nbrsel(tn2 >> 10);
        int mtn = tn2 & 1023;
        #pragma unroll
        for (int c = 0; c < 8; ++c) idxr[c] = nbrn[mtn * 64 + c * 8 + rowbase];
      }
    }
    __syncthreads();
  }
}

// Column-sum of partials [NTILE][HID] -> acc[HID]. 16 blocks x 64 cols.
__global__ __launch_bounds__(256) void k_reduce(const float* __restrict__ partials,
                                                float* __restrict__ acc) {
  __shared__ float red[4][64];
  int tid = threadIdx.x;
  int c = tid & 63, rg = tid >> 6;
  int col = blockIdx.x * 64 + c;
  float s = 0.f;
  #pragma unroll 4
  for (int r = rg; r < NTILE; r += 4)
    s += partials[(size_t)r * HID + col];
  red[rg][c] = s;
  __syncthreads();
  if (rg == 0) acc[col] = red[0][c] + red[1][c] + red[2][c] + red[3][c];
}

// pooled = acc/196608 ; feat_all = relu ; logits = feat_all @ Wc.T + bc
__global__ __launch_bounds__(256) void k_final(const float* __restrict__ acc,
                                               const float* __restrict__ Wc,
                                               const float* __restrict__ bc,
                                               float* __restrict__ out) {
  __shared__ float fall[HID];
  int tid = threadIdx.x;
  const float inv = 1.f / (3.f * (float)N_NBR);
  for (int i = tid; i < HID; i += 256) {
    float p = acc[i] * inv;
    fall[i] = (p > 0.f) ? p : 0.f;
  }
  __syncthreads();
  int o = tid >> 2, q = tid & 3;
  const f32x4* w = (const f32x4*)(Wc + (size_t)o * HID + q * 256);
  const f32x4* f = (const f32x4*)(fall + q * 256);
  float s = 0.f;
  #pragma unroll 4
  for (int k = 0; k < 64; ++k) {
    f32x4 wv = w[k], fv = f[k];
    s += wv.x * fv.x + wv.y * fv.y + wv.z * fv.z + wv.w * fv.w;
  }
  s += __shfl_xor(s, 1);
  s += __shfl_xor(s, 2);
  if (q == 0) out[o] = s + bc[o];
}

extern "C" void kernel_launch(void* const* d_in, const int* in_sizes, int n_in,
                              void* d_out, int out_size, void* d_ws, size_t ws_size,
                              hipStream_t stream) {
  // inputs: 0 feat(unused), 1 fa, 2 na, 3 W1a, 4 b1a, 5 fb, 6 nb, 7 W1b, 8 b1b,
  //         9 fc, 10 nc, 11 W1c, 12 b1c, 13 Wc, 14 bc
  const float* fa  = (const float*)d_in[1];
  const int*   na  = (const int*)d_in[2];
  const float* W1a = (const float*)d_in[3];
  const float* b1a = (const float*)d_in[4];
  const float* fb  = (const float*)d_in[5];
  const int*   nb  = (const int*)d_in[6];
  const float* W1b = (const float*)d_in[7];
  const float* b1b = (const float*)d_in[8];
  const float* fc  = (const float*)d_in[9];
  const int*   nc  = (const int*)d_in[10];
  const float* W1c = (const float*)d_in[11];
  const float* b1c = (const float*)d_in[12];
  const float* Wc  = (const float*)d_in[13];
  const float* bc  = (const float*)d_in[14];
  float* out = (float*)d_out;

  float* acc = (float*)d_ws;                                          // 1024 f32
  unsigned short* wbf = (unsigned short*)((char*)d_ws + 4096);        // 3 MB bf16 fragment-ordered
  float* partials = (float*)((char*)d_ws + 4096 + 3 * HID * INIT_DIM * sizeof(unsigned short)); // 12.6 MB

  k_convw<<<768, 256, 0, stream>>>(W1a, W1b, W1c, wbf);
  k_main<<<NBLOCK, 512, 0, stream>>>(fa, fb, fc, na, nb, nc, b1a, b1b, b1c, wbf, partials);
  k_reduce<<<16, 256, 0, stream>>>(partials, acc);
  k_final<<<1, 256, 0, stream>>>(acc, Wc, bc, out);
}

// Round 12
// 310.590 us; speedup vs baseline: 1.4941x; 1.0161x over previous
//
#include <hip/hip_runtime.h>
#include <hip/hip_bf16.h>

typedef __attribute__((ext_vector_type(8))) short short8v;
typedef __attribute__((ext_vector_type(8))) unsigned short ushort8v;
typedef __attribute__((ext_vector_type(4))) float f32x4;
typedef __attribute__((ext_vector_type(16))) float f32x16;

#define N_NBR 65536
#define INIT_DIM 512
#define HID 1024
#define BM 64
#define NTILE 3072     // 3 types x 1024 M-tiles
#define NBLOCK 256
#define PPB 6          // tile-PAIRS per block (1536 pairs / 256 blocks)

static __device__ __forceinline__ unsigned short f2bf(float f) {
  unsigned int u = __float_as_uint(f);
  u += 0x7fff + ((u >> 16) & 1);   // round-to-nearest-even
  return (unsigned short)(u >> 16);
}

// Relayout W (3x [1024 n][512 k] f32) into 32x32x16-MFMA fragment order bf16:
// tile (t, nb 0..31, ks 0..31): the 1KB a wave reads is contiguous:
//   out[(((t*32+nb)*32)+ks)*512 + l*8 + j] = W_t[nb*32 + (l&31)][ks*16 + (l>>5)*8 + j]
__global__ __launch_bounds__(256) void k_convw(const float* __restrict__ wa,
                                               const float* __restrict__ wb,
                                               const float* __restrict__ wc,
                                               unsigned short* __restrict__ out) {
  int g = blockIdx.x * 256 + threadIdx.x;   // 0..196607
  int l = g & 63;
  int blk = g >> 6;            // t*1024 + nb*32 + ks
  int ks = blk & 31;
  int nb = (blk >> 5) & 31;
  int t = blk >> 10;
  const float* src = (t == 0) ? wa : (t == 1) ? wb : wc;
  int n = nb * 32 + (l & 31);
  int k0 = ks * 16 + (l >> 5) * 8;
  const f32x4* p = (const f32x4*)(src + (size_t)n * INIT_DIM + k0);
  f32x4 a = p[0], b = p[1];
  ushort8v v;
  v[0]=f2bf(a.x); v[1]=f2bf(a.y); v[2]=f2bf(a.z); v[3]=f2bf(a.w);
  v[4]=f2bf(b.x); v[5]=f2bf(b.y); v[6]=f2bf(b.z); v[7]=f2bf(b.w);
  *(ushort8v*)(out + (size_t)g * 8) = v;
}

// Main: 256 blocks x 512 threads (8 waves = 2/SIMD), 6 tile-PAIRS each.
// TWO 64-row A-tiles live in LDS (2 x 64KB); the K-loop computes BOTH tiles
// against each B fragment: 8 MFMA per 2 B-loads (R9/R11 had 4 per 2).
// Halves B-latency exposure per MFMA and halves device B traffic (3->1.5GB).
// R11 lesson: stage-hiding bought 0 (stage not critical path) -> barrier-
// separated staging, keep it simple. acc = 128 AGPR + ~110 VGPR <= 256 cap
// from __launch_bounds__(512,2) -> still 2 waves/SIMD.
__global__ __launch_bounds__(512, 2) void k_main(
    const float* __restrict__ fa, const float* __restrict__ fb, const float* __restrict__ fc,
    const int* __restrict__ na, const int* __restrict__ nb_, const int* __restrict__ nc__,
    const float* __restrict__ b1a, const float* __restrict__ b1b, const float* __restrict__ b1c,
    const unsigned short* __restrict__ wbf,   // [3][32 nb][32 ks][512] fragment-ordered bf16
    float* __restrict__ partials) {           // [NTILE][HID]
  __shared__ __align__(16) unsigned short Asm[2][BM * INIT_DIM];  // 2 x 64 KB

  int bx = blockIdx.x;
  int tid = threadIdx.x;
  int wave = tid >> 6;          // 0..7
  int lane = tid & 63;
  int l31 = lane & 31, hi = lane >> 5;

  // A-read swizzle algebra (R9): byte = row*1024 + ((ks*32+hi*16) ^ (l31<<4));
  // row = i*32 + l31 so (row&31) == l31 -> mf-independent decomposition.
  unsigned int swz = (unsigned)l31 << 4;
  unsigned int abase = (unsigned)l31 * 1024u + (((unsigned)hi << 4) ^ (swz & 16u));
  unsigned int swzhi = swz & 0x1E0u;

  for (int jp = 0; jp < PPB; ++jp) {
    int pair = bx * PPB + jp;
    int t = pair >> 9;                 // 512 pairs per type
    int tile0 = pair * 2;              // global tile id (type-major)
    int mt0 = tile0 & 1023;
    const float* feat = (t == 0) ? fa : (t == 1) ? fb : fc;
    const int*   nbr  = (t == 0) ? na : (t == 1) ? nb_ : nc__;
    const float* bias = (t == 0) ? b1a : (t == 1) ? b1b : b1c;
    const unsigned short* Wf = wbf + (size_t)t * (HID * INIT_DIM);

    if (jp) __syncthreads();   // prior round's LDS readers done

    // Stage BOTH tiles: wave w stages rows {c*8+w}, lane = 8-float chunk.
    #pragma unroll
    for (int tl = 0; tl < 2; ++tl) {
      int idxr[8];
      #pragma unroll
      for (int c = 0; c < 8; ++c) idxr[c] = nbr[(mt0 + tl) * 64 + c * 8 + wave];
      #pragma unroll 4
      for (int c = 0; c < 8; ++c) {
        const float* rp = feat + (size_t)idxr[c] * INIT_DIM + lane * 8;
        f32x4 a = __builtin_nontemporal_load((const f32x4*)rp);
        f32x4 b2 = __builtin_nontemporal_load((const f32x4*)rp + 1);
        ushort8v v;
        v[0]=f2bf(a.x); v[1]=f2bf(a.y); v[2]=f2bf(a.z); v[3]=f2bf(a.w);
        v[4]=f2bf(b2.x); v[5]=f2bf(b2.y); v[6]=f2bf(b2.z); v[7]=f2bf(b2.w);
        int r = c * 8 + wave;
        unsigned byte = (unsigned)r * 1024u + (((unsigned)lane * 16u) ^ ((unsigned)(r & 31) << 4));
        *(ushort8v*)((char*)&Asm[tl][0] + byte) = v;
      }
    }
    __syncthreads();

    #pragma unroll
    for (int p = 0; p < 2; ++p) {
      // B base: nb index = wave*4 + p*2 + j in [0,32)
      const unsigned short* pB0 = Wf + (((size_t)(wave * 4 + p * 2)) << 14) + lane * 8;

      f32x16 acc[2][2][2] = {};   // [tile][mf][nf] -> 128 AGPR
      #pragma unroll 4
      for (int ks = 0; ks < 32; ++ks) {
        short8v Bf[2];
        #pragma unroll
        for (int j = 0; j < 2; ++j)
          Bf[j] = *(const short8v*)(pB0 + (j << 14) + (ks << 9));
        unsigned kcol = (((unsigned)ks << 5) ^ swzhi);
        short8v Af[2][2];
        #pragma unroll
        for (int tl = 0; tl < 2; ++tl)
          #pragma unroll
          for (int i = 0; i < 2; ++i)
            Af[tl][i] = *(const short8v*)((const char*)&Asm[0][0] +
                          (unsigned)(tl * 65536) + abase + (unsigned)(i * 32768) + kcol);
        #pragma unroll
        for (int tl = 0; tl < 2; ++tl)
          #pragma unroll
          for (int i = 0; i < 2; ++i)
            #pragma unroll
            for (int j = 0; j < 2; ++j)
              acc[tl][i][j] = __builtin_amdgcn_mfma_f32_32x32x16_bf16(
                  Af[tl][i], Bf[j], acc[tl][i][j], 0, 0, 0);
      }

      // Epilogue: bias + relu + col-sum over 64 rows per tile -> partials.
      // C layout (32x32): col = l31, row = (reg&3)+8*(reg>>2)+4*hi (+32*i).
      #pragma unroll
      for (int tl = 0; tl < 2; ++tl) {
        #pragma unroll
        for (int j = 0; j < 2; ++j) {
          int n = wave * 128 + p * 64 + j * 32 + l31;
          float b = bias[n];
          float s = 0.f;
          #pragma unroll
          for (int i = 0; i < 2; ++i)
            #pragma unroll
            for (int r = 0; r < 16; ++r) {
              float v = acc[tl][i][j][r] + b;
              s += (v > 0.f) ? v : 0.f;
            }
          s += __shfl_xor(s, 32);
          if (hi == 0) partials[(size_t)(tile0 + tl) * HID + n] = s;
        }
      }
    }
  }
}

// Column-sum of partials [NTILE][HID] -> acc[HID]. 16 blocks x 64 cols.
__global__ __launch_bounds__(256) void k_reduce(const float* __restrict__ partials,
                                                float* __restrict__ acc) {
  __shared__ float red[4][64];
  int tid = threadIdx.x;
  int c = tid & 63, rg = tid >> 6;
  int col = blockIdx.x * 64 + c;
  float s = 0.f;
  #pragma unroll 4
  for (int r = rg; r < NTILE; r += 4)
    s += partials[(size_t)r * HID + col];
  red[rg][c] = s;
  __syncthreads();
  if (rg == 0) acc[col] = red[0][c] + red[1][c] + red[2][c] + red[3][c];
}

// pooled = acc/196608 ; feat_all = relu ; logits = feat_all @ Wc.T + bc
__global__ __launch_bounds__(256) void k_final(const float* __restrict__ acc,
                                               const float* __restrict__ Wc,
                                               const float* __restrict__ bc,
                                               float* __restrict__ out) {
  __shared__ float fall[HID];
  int tid = threadIdx.x;
  const float inv = 1.f / (3.f * (float)N_NBR);
  for (int i = tid; i < HID; i += 256) {
    float p = acc[i] * inv;
    fall[i] = (p > 0.f) ? p : 0.f;
  }
  __syncthreads();
  int o = tid >> 2, q = tid & 3;
  const f32x4* w = (const f32x4*)(Wc + (size_t)o * HID + q * 256);
  const f32x4* f = (const f32x4*)(fall + q * 256);
  float s = 0.f;
  #pragma unroll 4
  for (int k = 0; k < 64; ++k) {
    f32x4 wv = w[k], fv = f[k];
    s += wv.x * fv.x + wv.y * fv.y + wv.z * fv.z + wv.w * fv.w;
  }
  s += __shfl_xor(s, 1);
  s += __shfl_xor(s, 2);
  if (q == 0) out[o] = s + bc[o];
}

extern "C" void kernel_launch(void* const* d_in, const int* in_sizes, int n_in,
                              void* d_out, int out_size, void* d_ws, size_t ws_size,
                              hipStream_t stream) {
  // inputs: 0 feat(unused), 1 fa, 2 na, 3 W1a, 4 b1a, 5 fb, 6 nb, 7 W1b, 8 b1b,
  //         9 fc, 10 nc, 11 W1c, 12 b1c, 13 Wc, 14 bc
  const float* fa  = (const float*)d_in[1];
  const int*   na  = (const int*)d_in[2];
  const float* W1a = (const float*)d_in[3];
  const float* b1a = (const float*)d_in[4];
  const float* fb  = (const float*)d_in[5];
  const int*   nb  = (const int*)d_in[6];
  const float* W1b = (const float*)d_in[7];
  const float* b1b = (const float*)d_in[8];
  const float* fc  = (const float*)d_in[9];
  const int*   nc  = (const int*)d_in[10];
  const float* W1c = (const float*)d_in[11];
  const float* b1c = (const float*)d_in[12];
  const float* Wc  = (const float*)d_in[13];
  const float* bc  = (const float*)d_in[14];
  float* out = (float*)d_out;

  float* acc = (float*)d_ws;                                          // 1024 f32
  unsigned short* wbf = (unsigned short*)((char*)d_ws + 4096);        // 3 MB bf16 fragment-ordered
  float* partials = (float*)((char*)d_ws + 4096 + 3 * HID * INIT_DIM * sizeof(unsigned short)); // 12.6 MB

  k_convw<<<768, 256, 0, stream>>>(W1a, W1b, W1c, wbf);
  k_main<<<NBLOCK, 512, 0, stream>>>(fa, fb, fc, na, nb, nc, b1a, b1b, b1c, wbf, partials);
  k_reduce<<<16, 256, 0, stream>>>(partials, acc);
  k_final<<<1, 256, 0, stream>>>(acc, Wc, bc, out);
}